// Round 9
// baseline (1351.793 us; speedup 1.0000x reference)
//
#include <hip/hip_runtime.h>

// N=1024, D=16, H=32, 3H=96.  All tensors fp32 (per reference dtypes).

typedef _Float16 hv2 __attribute__((ext_vector_type(2)));

__device__ __forceinline__ unsigned rlu(unsigned v, int k) {
    return (unsigned)__builtin_amdgcn_readlane((int)v, k);
}
// pack two fp32 -> half2 bits (v_cvt_pkrtz_f16_f32)
__device__ __forceinline__ unsigned pkh(float a, float b) {
    auto t = __builtin_amdgcn_cvt_pkrtz(a, b);
    return __builtin_bit_cast(unsigned, t);
}
// dot2: c += a.x*b.x + a.y*b.y   (f16 inputs, f32 accumulate)
#if __has_builtin(__builtin_amdgcn_fdot2)
__device__ __forceinline__ float d2(unsigned a, unsigned b, float c) {
    return __builtin_amdgcn_fdot2(__builtin_bit_cast(hv2, a),
                                  __builtin_bit_cast(hv2, b), c, false);
}
#else
__device__ __forceinline__ float d2(unsigned a, unsigned b, float c) {
    hv2 x = __builtin_bit_cast(hv2, a), y = __builtin_bit_cast(hv2, b);
    return fmaf((float)x.x, (float)y.x, fmaf((float)x.y, (float)y.y, c));
}
#endif
// neighbor (lane^1) via DPP quad_perm(1,0,3,2) -- VALU, no LDS
#if __has_builtin(__builtin_amdgcn_mov_dpp)
__device__ __forceinline__ float nbr1(float v) {
    return __int_as_float(
        __builtin_amdgcn_mov_dpp(__float_as_int(v), 0xB1, 0xF, 0xF, true));
}
#else
__device__ __forceinline__ float nbr1(float v) {
    return __int_as_float(__builtin_amdgcn_ds_swizzle(__float_as_int(v), 0x041F));
}
#endif

// ---------------------------------------------------------------------------
// K1: stage-1 pairwise split.  A[i,h] = sum_d (w[h,d]-w[h,16+d])*x[i,d] + b[h]
//                              B[j,h] = sum_d w[h,16+d]*x[j,d]
// relu(A[i,:]+B[j,:]) reconstructs out1[i,j,:] -- [N,N,H] never materialized.
// ---------------------------------------------------------------------------
__global__ void proj1_kernel(const float* __restrict__ x, const float* __restrict__ w,
                             const float* __restrict__ bias,
                             float* __restrict__ A, float* __restrict__ B) {
    int idx = blockIdx.x * 256 + threadIdx.x;      // 0..32767
    int i = idx >> 5, h = idx & 31;
    float sa = bias[h];
    float sb = 0.f;
#pragma unroll
    for (int d = 0; d < 16; ++d) {
        float xv = x[i * 16 + d];
        float wa = w[h * 32 + d];
        float wb = w[h * 32 + 16 + d];
        sa += (wa - wb) * xv;
        sb += wb * xv;
    }
    A[i * 32 + h] = sa;
    B[i * 32 + h] = sb;
}

__global__ void proj2_kernel(const float* __restrict__ h1, const float* __restrict__ w,
                             const float* __restrict__ bias,
                             float* __restrict__ A, float* __restrict__ B) {
    int idx = blockIdx.x * 256 + threadIdx.x;      // 0..32767
    int i = idx >> 5, h = idx & 31;
    float sa = bias[h];
    float sb = 0.f;
#pragma unroll
    for (int k = 0; k < 32; ++k) {
        float hv = h1[i * 32 + k];
        float wa = w[h * 64 + k];
        float wb = w[h * 64 + 32 + k];
        sa += (wa - wb) * hv;
        sb += wb * hv;
    }
    A[i * 32 + h] = sa;
    B[i * 32 + h] = sb;
}

// ---------------------------------------------------------------------------
// GRU: TWO independent chains TIME-INTERLEAVED in one wave (R6 structure x2).
// Chain cA = 2*blockIdx, cB = 2*blockIdx+1.  Both use the full wave with the
// R6 lane-mapping (l<32: r-row l, l>=32: z-row l; n-row 64+m replicated),
// SHARED weight registers and SHARED B[t] loads; separate h/x state.  Chain
// B's ~240 issue cycles fill chain A's dependency-stall windows.  H-dots are
// split into 2x8-deep accumulators to halve the dot-chain latency.  o/h
// broadcasts: DPP pair-pack + 16 v_readlane -> SGPR -> v_dot2 (the measured
// best path; ds_swizzle broadcast ruled out by R8).
// ---------------------------------------------------------------------------
__global__ __launch_bounds__(64, 1) void gru_kernel(
    const float* __restrict__ A, const float* __restrict__ B,
    const float* __restrict__ wih, const float* __restrict__ whh,
    const float* __restrict__ bih, const float* __restrict__ bhh,
    float* __restrict__ h_out) {
    const int l = threadIdx.x;        // 0..63
    const int m = l & 31;
    const int cA = blockIdx.x * 2;
    const int cB = cA + 1;

    // shared packed weight rows (64 VGPRs):
    //   wA2 = wih[l] (r-row l<32 / z-row l>=32, x-side); wB2 = whh[l] (h-side)
    //   wC2 = wih[64+m] (n x-side, replicated); wD2 = whh[64+m] (n h-side)
    unsigned wA2[16], wB2[16], wC2[16], wD2[16];
#pragma unroll
    for (int k = 0; k < 16; ++k) {
        wA2[k] = pkh(wih[l * 32 + 2 * k], wih[l * 32 + 2 * k + 1]);
        wB2[k] = pkh(whh[l * 32 + 2 * k], whh[l * 32 + 2 * k + 1]);
        wC2[k] = pkh(wih[(64 + m) * 32 + 2 * k], wih[(64 + m) * 32 + 2 * k + 1]);
        wD2[k] = pkh(whh[(64 + m) * 32 + 2 * k], whh[(64 + m) * 32 + 2 * k + 1]);
    }
    const float b1 = bih[l] + bhh[l];      // fused r/z bias (row l)
    const float bx = bih[64 + m];          // n-gate x bias
    const float bh = bhh[64 + m];          // n-gate h bias

    const float aA = A[cA * 32 + m];
    const float aB = A[cB * 32 + m];
    float hA = 0.f, hB = 0.f;              // h_m replicated in both halves

    unsigned huA[16], huB[16];             // wave-uniform packed h
#pragma unroll
    for (int k = 0; k < 16; ++k) { huA[k] = 0u; huB[k] = 0u; }

    // ---- prologue: X-phase for t=0, both chains ----
    float xg1A, xgnA, xg1B, xgnB;
    {
        float b0 = B[m];
        float oA = fmaxf(aA + b0, 0.f);
        float oB = fmaxf(aB + b0, 0.f);
        unsigned opkA = pkh(oA, nbr1(oA));
        unsigned opkB = pkh(oB, nbr1(oB));
        xg1A = b1; xgnA = bx; xg1B = b1; xgnB = bx;
#pragma unroll
        for (int k = 0; k < 16; ++k) {
            unsigned okA = rlu(opkA, 2 * k);
            unsigned okB = rlu(opkB, 2 * k);
            xg1A = d2(wA2[k], okA, xg1A);
            xgnA = d2(wC2[k], okA, xgnA);
            xg1B = d2(wA2[k], okB, xg1B);
            xgnB = d2(wC2[k], okB, xgnB);
        }
    }
    float b_next = B[32 + m];              // shared B row for t=1

    for (int t = 0; t < 1024; ++t) {
        float b_pref = B[((t + 2) & 1023) * 32 + m];   // shared prefetch

        // ---- H-dots, both chains, 2x8-deep split accumulators ----
        float h1A0 = 0.f, h1A1 = 0.f, hnA0 = bh, hnA1 = 0.f;
        float h1B0 = 0.f, h1B1 = 0.f, hnB0 = bh, hnB1 = 0.f;
#pragma unroll
        for (int k = 0; k < 8; ++k) {
            h1A0 = d2(wB2[k],     huA[k],     h1A0);
            h1A1 = d2(wB2[k + 8], huA[k + 8], h1A1);
            hnA0 = d2(wD2[k],     huA[k],     hnA0);
            hnA1 = d2(wD2[k + 8], huA[k + 8], hnA1);
            h1B0 = d2(wB2[k],     huB[k],     h1B0);
            h1B1 = d2(wB2[k + 8], huB[k + 8], h1B1);
            hnB0 = d2(wD2[k],     huB[k],     hnB0);
            hnB1 = d2(wD2[k + 8], huB[k + 8], hnB1);
        }
        float hg1A = h1A0 + h1A1, hgnA = hnA0 + hnA1;
        float hg1B = h1B0 + h1B1, hgnB = hnB0 + hnB1;

        // ---- X-phase for t+1, both chains (h-independent filler) ----
        float nxg1A = b1, nxgnA = bx, nxg1B = b1, nxgnB = bx;
        {
            float oA = fmaxf(aA + b_next, 0.f);
            float oB = fmaxf(aB + b_next, 0.f);
            unsigned opkA = pkh(oA, nbr1(oA));
            unsigned opkB = pkh(oB, nbr1(oB));
#pragma unroll
            for (int k = 0; k < 16; ++k) {
                unsigned okA = rlu(opkA, 2 * k);
                unsigned okB = rlu(opkB, 2 * k);
                nxg1A = d2(wA2[k], okA, nxg1A);
                nxgnA = d2(wC2[k], okA, nxgnA);
                nxg1B = d2(wA2[k], okB, nxg1B);
                nxgnB = d2(wC2[k], okB, nxgnB);
            }
        }

        // ---- gates chain A ----
        float sgA = 1.f / (1.f + __expf(-(xg1A + hg1A)));
        float rrA = __shfl(sgA, m);         // r_m
        float zzA = __shfl(sgA, m + 32);    // z_m
        float npA = xgnA + rrA * hgnA;
        float nA = 1.f - 2.f / (__expf(2.f * npA) + 1.f);
        hA = (1.f - zzA) * nA + zzA * hA;
        unsigned hpkA = pkh(hA, nbr1(hA));

        // ---- gates chain B ----
        float sgB = 1.f / (1.f + __expf(-(xg1B + hg1B)));
        float rrB = __shfl(sgB, m);
        float zzB = __shfl(sgB, m + 32);
        float npB = xgnB + rrB * hgnB;
        float nB = 1.f - 2.f / (__expf(2.f * npB) + 1.f);
        hB = (1.f - zzB) * nB + zzB * hB;
        unsigned hpkB = pkh(hB, nbr1(hB));

        // ---- h broadcasts for t+1 ----
#pragma unroll
        for (int k = 0; k < 16; ++k) {
            huA[k] = rlu(hpkA, 2 * k);
            huB[k] = rlu(hpkB, 2 * k);
        }

        xg1A = nxg1A; xgnA = nxgnA;
        xg1B = nxg1B; xgnB = nxgnB;
        b_next = b_pref;
    }

    if (l < 32) {
        h_out[cA * 32 + m] = hA;
        h_out[cB * 32 + m] = hB;
    }
}

// ---------------------------------------------------------------------------
// K5: classifier. out[i,o] = sum_k clf_w[o,k]*h2[i,k] + clf_b[o]  (fp32 out)
// ---------------------------------------------------------------------------
__global__ void clf_kernel(const float* __restrict__ h2v, const float* __restrict__ w,
                           const float* __restrict__ bias, float* __restrict__ out) {
    int idx = blockIdx.x * 256 + threadIdx.x;      // 0..3071
    if (idx >= 3072) return;
    int i = idx / 3, o = idx - i * 3;
    float s = bias[o];
#pragma unroll
    for (int k = 0; k < 32; ++k) s += w[o * 32 + k] * h2v[i * 32 + k];
    out[idx] = s;
}

extern "C" void kernel_launch(void* const* d_in, const int* in_sizes, int n_in,
                              void* d_out, int out_size, void* d_ws, size_t ws_size,
                              hipStream_t stream) {
    const float* x       = (const float*)d_in[0];
    const float* p1w     = (const float*)d_in[1];
    const float* p1b     = (const float*)d_in[2];
    const float* g1_wih  = (const float*)d_in[3];
    const float* g1_whh  = (const float*)d_in[4];
    const float* g1_bih  = (const float*)d_in[5];
    const float* g1_bhh  = (const float*)d_in[6];
    const float* p2w     = (const float*)d_in[7];
    const float* p2b     = (const float*)d_in[8];
    const float* g2_wih  = (const float*)d_in[9];
    const float* g2_whh  = (const float*)d_in[10];
    const float* g2_bih  = (const float*)d_in[11];
    const float* g2_bhh  = (const float*)d_in[12];
    const float* clfw    = (const float*)d_in[13];
    const float* clfb    = (const float*)d_in[14];

    // Workspace layout (reused across stages; 3 x 32768 floats = 384 KB):
    float* ws = (float*)d_ws;
    float* A  = ws;              // A1 then A2
    float* Bt = ws + 32768;      // B1 then B2
    float* h  = ws + 65536;      // h1 then h2

    proj1_kernel<<<128, 256, 0, stream>>>(x, p1w, p1b, A, Bt);
    gru_kernel<<<512, 64, 0, stream>>>(A, Bt, g1_wih, g1_whh, g1_bih, g1_bhh, h);
    proj2_kernel<<<128, 256, 0, stream>>>(h, p2w, p2b, A, Bt);
    gru_kernel<<<512, 64, 0, stream>>>(A, Bt, g2_wih, g2_whh, g2_bih, g2_bhh, h);
    clf_kernel<<<12, 256, 0, stream>>>(h, clfw, clfb, (float*)d_out);
}

// Round 10
// 1314.096 us; speedup vs baseline: 1.0287x; 1.0287x over previous
//
#include <hip/hip_runtime.h>

// N=1024, D=16, H=32, 3H=96.  All tensors fp32 (per reference dtypes).

typedef _Float16 hv2 __attribute__((ext_vector_type(2)));
typedef _Float16 hv8 __attribute__((ext_vector_type(8)));
typedef float    fv4 __attribute__((ext_vector_type(4)));
typedef unsigned uv4 __attribute__((ext_vector_type(4)));

// pack two fp32 -> f16 pair bits (v_cvt_pkrtz_f16_f32)
__device__ __forceinline__ unsigned pkh(float a, float b) {
    auto t = __builtin_amdgcn_cvt_pkrtz(a, b);
    return __builtin_bit_cast(unsigned, t);
}

// ---------------------------------------------------------------------------
// K1: stage-1 pairwise split.  A[i,h] = sum_d (w[h,d]-w[h,16+d])*x[i,d] + b[h]
//                              B[j,h] = sum_d w[h,16+d]*x[j,d]
// relu(A[i,:]+B[j,:]) reconstructs out1[i,j,:] -- [N,N,H] never materialized.
// ---------------------------------------------------------------------------
__global__ void proj1_kernel(const float* __restrict__ x, const float* __restrict__ w,
                             const float* __restrict__ bias,
                             float* __restrict__ A, float* __restrict__ B) {
    int idx = blockIdx.x * 256 + threadIdx.x;      // 0..32767
    int i = idx >> 5, h = idx & 31;
    float sa = bias[h];
    float sb = 0.f;
#pragma unroll
    for (int d = 0; d < 16; ++d) {
        float xv = x[i * 16 + d];
        float wa = w[h * 32 + d];
        float wb = w[h * 32 + 16 + d];
        sa += (wa - wb) * xv;
        sb += wb * xv;
    }
    A[i * 32 + h] = sa;
    B[i * 32 + h] = sb;
}

__global__ void proj2_kernel(const float* __restrict__ h1, const float* __restrict__ w,
                             const float* __restrict__ bias,
                             float* __restrict__ A, float* __restrict__ B) {
    int idx = blockIdx.x * 256 + threadIdx.x;      // 0..32767
    int i = idx >> 5, h = idx & 31;
    float sa = bias[h];
    float sb = 0.f;
#pragma unroll
    for (int k = 0; k < 32; ++k) {
        float hv = h1[i * 32 + k];
        float wa = w[h * 64 + k];
        float wb = w[h * 64 + 32 + k];
        sa += (wa - wb) * hv;
        sb += wb * hv;
    }
    A[i * 32 + h] = sa;
    B[i * 32 + h] = sb;
}

// ---------------------------------------------------------------------------
// GRU via MFMA.  4 chains per wave, 256 blocks (1 wave/CU).
//
// k-slot permutation (applied identically to A-frags and weight B-frags):
//   slot (q = lane>>4, j = 0..7):  k = 4q + (j>>1) + 16*(j&1)
//   i.e. f16 pair p = 4q + reg holds (k=p, k=p+16).
//
// A-frag (16x16x32, A[m][k], m=lane&15, k=quad*8+j): row m -> chain m>>2
//   (each chain's rows replicated 4x).  X-frag built from fp32 A/B rows
//   (relu in fp32), h-frag pulled with 4 ds_bpermute from the h-pair layout.
// B-frags: 6 tiles x {wih,whh}; tile T, lane: gate g = 16T + (lane&15),
//   reg r = pkh(w[g][4q+r], w[g][4q+r+16]).  Loop-invariant, 48 VGPRs.
// C/D (col=lane&15, row=quad*4+reg): lane l holds gates g≡(l&15) (mod 16)
//   of chain q=l>>4, all 4 regs identical -> use reg[0].  So lane l owns
//   (chain q, m0=l&15): r/z/xn/hn for m0 and m0+16 all IN-LANE; h-update
//   in-lane; h-pair pkh(h_m0, h_m0+16) lands at lane q*16+m0 == l.  The only
//   cross-lane op per step: 4 ds_bpermute (h-pairs -> next A-frag).
// Gate tiles: T0,1=r  T2,3=z  T4,5=n.  r/z h-MFMAs accumulate onto x-side
// pre-acts (C chaining); n keeps x/h parts separate (n = tanh(xn + r*hn)).
// X-side MFMAs for t+1 issue inside step t (h-independent filler).
// ---------------------------------------------------------------------------
__global__ __launch_bounds__(64, 1) void gru_kernel(
    const float* __restrict__ A, const float* __restrict__ B,
    const float* __restrict__ wih, const float* __restrict__ whh,
    const float* __restrict__ bih, const float* __restrict__ bhh,
    float* __restrict__ h_out) {
    const int l = threadIdx.x;         // 0..63
    const int q = l >> 4;              // k-group; also the chain whose gates we own
    const int m0 = l & 15;             // gate col / hidden index (and m0+16)
    const int crow = m0 >> 2;          // chain owning A-frag row m0 (block-local)
    const int cbase = blockIdx.x * 4;

    // ---- loop-invariant weight B-frags ----
    hv8 WI[6], WH[6];
#pragma unroll
    for (int T = 0; T < 6; ++T) {
        int g = 16 * T + m0;
        uv4 wi, wh;
#pragma unroll
        for (int r = 0; r < 4; ++r) {
            int lo = 4 * q + r, hi = lo + 16;
            wi[r] = pkh(wih[g * 32 + lo], wih[g * 32 + hi]);
            wh[r] = pkh(whh[g * 32 + lo], whh[g * 32 + hi]);
        }
        WI[T] = __builtin_bit_cast(hv8, wi);
        WH[T] = __builtin_bit_cast(hv8, wh);
    }
    // ---- bias C-frags (value depends only on gate col -> splat) ----
    fv4 CRZ[4], CXN[2], CHN[2];
#pragma unroll
    for (int T = 0; T < 4; ++T) {
        float v = bih[16 * T + m0] + bhh[16 * T + m0];
        CRZ[T] = fv4{v, v, v, v};
    }
#pragma unroll
    for (int T = 4; T < 6; ++T) {
        float vx = bih[16 * T + m0], vh = bhh[16 * T + m0];
        CXN[T - 4] = fv4{vx, vx, vx, vx};
        CHN[T - 4] = fv4{vh, vh, vh, vh};
    }

    // ---- static per-row A chunks (fp32) ----
    const fv4* A4 = (const fv4*)A;     // [chain*8 + chunk]
    const fv4* B4 = (const fv4*)B;     // [t*8 + chunk]
    const fv4 alo = A4[(cbase + crow) * 8 + q];
    const fv4 ahi = A4[(cbase + crow) * 8 + 4 + q];

    const int baddr = (crow * 16 + 4 * q) * 4;   // bpermute byte addr base

    float h0 = 0.f, h1 = 0.f;          // h_{m0}, h_{m0+16} of chain q
    unsigned hpair = 0u;               // pkh(h0,h1) -> pair m0 of chain q

    // ---- prologue: X pre-acts for t=0 ----
    fv4 X0, X1, X2, X3, X4, X5;
    {
        fv4 blo = B4[q], bhi = B4[4 + q];
        uv4 xb;
#pragma unroll
        for (int r = 0; r < 4; ++r)
            xb[r] = pkh(fmaxf(alo[r] + blo[r], 0.f), fmaxf(ahi[r] + bhi[r], 0.f));
        hv8 xf = __builtin_bit_cast(hv8, xb);
        X0 = __builtin_amdgcn_mfma_f32_16x16x32_f16(xf, WI[0], CRZ[0], 0, 0, 0);
        X1 = __builtin_amdgcn_mfma_f32_16x16x32_f16(xf, WI[1], CRZ[1], 0, 0, 0);
        X2 = __builtin_amdgcn_mfma_f32_16x16x32_f16(xf, WI[2], CRZ[2], 0, 0, 0);
        X3 = __builtin_amdgcn_mfma_f32_16x16x32_f16(xf, WI[3], CRZ[3], 0, 0, 0);
        X4 = __builtin_amdgcn_mfma_f32_16x16x32_f16(xf, WI[4], CXN[0], 0, 0, 0);
        X5 = __builtin_amdgcn_mfma_f32_16x16x32_f16(xf, WI[5], CXN[1], 0, 0, 0);
    }
    fv4 blo = B4[8 + q], bhi = B4[8 + 4 + q];    // B row t=1

#pragma unroll 2
    for (int t = 0; t < 1024; ++t) {
        int t2 = (t + 2) & 1023;
        fv4 plo = B4[t2 * 8 + q], phi = B4[t2 * 8 + 4 + q];   // dist-2 prefetch

        // ---- h A-frag: 4 bpermutes of the wave's h-pairs ----
        uv4 hp;
        hp[0] = (unsigned)__builtin_amdgcn_ds_bpermute(baddr,      (int)hpair);
        hp[1] = (unsigned)__builtin_amdgcn_ds_bpermute(baddr + 4,  (int)hpair);
        hp[2] = (unsigned)__builtin_amdgcn_ds_bpermute(baddr + 8,  (int)hpair);
        hp[3] = (unsigned)__builtin_amdgcn_ds_bpermute(baddr + 12, (int)hpair);
        hv8 hf = __builtin_bit_cast(hv8, hp);

        // ---- h-side MFMAs: r/z accumulate onto x pre-acts, n separate ----
        fv4 G0 = __builtin_amdgcn_mfma_f32_16x16x32_f16(hf, WH[0], X0, 0, 0, 0);
        fv4 G1 = __builtin_amdgcn_mfma_f32_16x16x32_f16(hf, WH[1], X1, 0, 0, 0);
        fv4 G2 = __builtin_amdgcn_mfma_f32_16x16x32_f16(hf, WH[2], X2, 0, 0, 0);
        fv4 G3 = __builtin_amdgcn_mfma_f32_16x16x32_f16(hf, WH[3], X3, 0, 0, 0);
        fv4 H4 = __builtin_amdgcn_mfma_f32_16x16x32_f16(hf, WH[4], CHN[0], 0, 0, 0);
        fv4 H5 = __builtin_amdgcn_mfma_f32_16x16x32_f16(hf, WH[5], CHN[1], 0, 0, 0);

        // ---- X phase for t+1 (independent filler) ----
        uv4 xb;
#pragma unroll
        for (int r = 0; r < 4; ++r)
            xb[r] = pkh(fmaxf(alo[r] + blo[r], 0.f), fmaxf(ahi[r] + bhi[r], 0.f));
        hv8 xf = __builtin_bit_cast(hv8, xb);
        fv4 NX0 = __builtin_amdgcn_mfma_f32_16x16x32_f16(xf, WI[0], CRZ[0], 0, 0, 0);
        fv4 NX1 = __builtin_amdgcn_mfma_f32_16x16x32_f16(xf, WI[1], CRZ[1], 0, 0, 0);
        fv4 NX2 = __builtin_amdgcn_mfma_f32_16x16x32_f16(xf, WI[2], CRZ[2], 0, 0, 0);
        fv4 NX3 = __builtin_amdgcn_mfma_f32_16x16x32_f16(xf, WI[3], CRZ[3], 0, 0, 0);
        fv4 NX4 = __builtin_amdgcn_mfma_f32_16x16x32_f16(xf, WI[4], CXN[0], 0, 0, 0);
        fv4 NX5 = __builtin_amdgcn_mfma_f32_16x16x32_f16(xf, WI[5], CXN[1], 0, 0, 0);

        // ---- gates + update, fully in-lane (reg[0] of each D-frag) ----
        float r0 = 1.f / (1.f + __expf(-G0[0]));
        float r1 = 1.f / (1.f + __expf(-G1[0]));
        float z0 = 1.f / (1.f + __expf(-G2[0]));
        float z1 = 1.f / (1.f + __expf(-G3[0]));
        float n0 = 1.f - 2.f / (__expf(2.f * (X4[0] + r0 * H4[0])) + 1.f);
        float n1 = 1.f - 2.f / (__expf(2.f * (X5[0] + r1 * H5[0])) + 1.f);
        h0 = (1.f - z0) * n0 + z0 * h0;
        h1 = (1.f - z1) * n1 + z1 * h1;
        hpair = pkh(h0, h1);

        X0 = NX0; X1 = NX1; X2 = NX2; X3 = NX3; X4 = NX4; X5 = NX5;
        blo = plo; bhi = phi;
    }

    h_out[(cbase + q) * 32 + m0]      = h0;
    h_out[(cbase + q) * 32 + m0 + 16] = h1;
}

// ---------------------------------------------------------------------------
// K5: classifier. out[i,o] = sum_k clf_w[o,k]*h2[i,k] + clf_b[o]  (fp32 out)
// ---------------------------------------------------------------------------
__global__ void clf_kernel(const float* __restrict__ h2v, const float* __restrict__ w,
                           const float* __restrict__ bias, float* __restrict__ out) {
    int idx = blockIdx.x * 256 + threadIdx.x;      // 0..3071
    if (idx >= 3072) return;
    int i = idx / 3, o = idx - i * 3;
    float s = bias[o];
#pragma unroll
    for (int k = 0; k < 32; ++k) s += w[o * 32 + k] * h2v[i * 32 + k];
    out[idx] = s;
}

extern "C" void kernel_launch(void* const* d_in, const int* in_sizes, int n_in,
                              void* d_out, int out_size, void* d_ws, size_t ws_size,
                              hipStream_t stream) {
    const float* x       = (const float*)d_in[0];
    const float* p1w     = (const float*)d_in[1];
    const float* p1b     = (const float*)d_in[2];
    const float* g1_wih  = (const float*)d_in[3];
    const float* g1_whh  = (const float*)d_in[4];
    const float* g1_bih  = (const float*)d_in[5];
    const float* g1_bhh  = (const float*)d_in[6];
    const float* p2w     = (const float*)d_in[7];
    const float* p2b     = (const float*)d_in[8];
    const float* g2_wih  = (const float*)d_in[9];
    const float* g2_whh  = (const float*)d_in[10];
    const float* g2_bih  = (const float*)d_in[11];
    const float* g2_bhh  = (const float*)d_in[12];
    const float* clfw    = (const float*)d_in[13];
    const float* clfb    = (const float*)d_in[14];

    // Workspace layout (reused across stages; 3 x 32768 floats = 384 KB):
    float* ws = (float*)d_ws;
    float* A  = ws;              // A1 then A2
    float* Bt = ws + 32768;      // B1 then B2
    float* h  = ws + 65536;      // h1 then h2

    proj1_kernel<<<128, 256, 0, stream>>>(x, p1w, p1b, A, Bt);
    gru_kernel<<<256, 64, 0, stream>>>(A, Bt, g1_wih, g1_whh, g1_bih, g1_bhh, h);
    proj2_kernel<<<128, 256, 0, stream>>>(h, p2w, p2b, A, Bt);
    gru_kernel<<<256, 64, 0, stream>>>(A, Bt, g2_wih, g2_whh, g2_bih, g2_bhh, h);
    clf_kernel<<<12, 256, 0, stream>>>(h, clfw, clfb, (float*)d_out);
}

// Round 11
// 755.598 us; speedup vs baseline: 1.7890x; 1.7391x over previous
//
#include <hip/hip_runtime.h>

// N=1024, D=16, H=32, 3H=96.  All tensors fp32 (per reference dtypes).

typedef _Float16 hv8 __attribute__((ext_vector_type(8)));
typedef float    fv4 __attribute__((ext_vector_type(4)));
typedef unsigned uv4 __attribute__((ext_vector_type(4)));

// pack two fp32 -> f16 pair bits (v_cvt_pkrtz_f16_f32)
__device__ __forceinline__ unsigned pkh(float a, float b) {
    auto t = __builtin_amdgcn_cvt_pkrtz(a, b);
    return __builtin_bit_cast(unsigned, t);
}
__device__ __forceinline__ fv4 splat4(float v) { return fv4{v, v, v, v}; }

// ---------------------------------------------------------------------------
// K1: stage-1 pairwise split.  A[i,h] = sum_d (w[h,d]-w[h,16+d])*x[i,d] + b[h]
//                              B[j,h] = sum_d w[h,16+d]*x[j,d]
// relu(A[i,:]+B[j,:]) reconstructs out1[i,j,:] -- [N,N,H] never materialized.
// ---------------------------------------------------------------------------
__global__ void proj1_kernel(const float* __restrict__ x, const float* __restrict__ w,
                             const float* __restrict__ bias,
                             float* __restrict__ A, float* __restrict__ B) {
    int idx = blockIdx.x * 256 + threadIdx.x;      // 0..32767
    int i = idx >> 5, h = idx & 31;
    float sa = bias[h];
    float sb = 0.f;
#pragma unroll
    for (int d = 0; d < 16; ++d) {
        float xv = x[i * 16 + d];
        float wa = w[h * 32 + d];
        float wb = w[h * 32 + 16 + d];
        sa += (wa - wb) * xv;
        sb += wb * xv;
    }
    A[i * 32 + h] = sa;
    B[i * 32 + h] = sb;
}

__global__ void proj2_kernel(const float* __restrict__ h1, const float* __restrict__ w,
                             const float* __restrict__ bias,
                             float* __restrict__ A, float* __restrict__ B) {
    int idx = blockIdx.x * 256 + threadIdx.x;      // 0..32767
    int i = idx >> 5, h = idx & 31;
    float sa = bias[h];
    float sb = 0.f;
#pragma unroll
    for (int k = 0; k < 32; ++k) {
        float hv = h1[i * 32 + k];
        float wa = w[h * 64 + k];
        float wb = w[h * 64 + 32 + k];
        sa += (wa - wb) * hv;
        sb += wb * hv;
    }
    A[i * 32 + h] = sa;
    B[i * 32 + h] = sb;
}

// ---------------------------------------------------------------------------
// GRU via MFMA, ONE chain per wave (1024 blocks), X-side offloaded per-chunk.
//
// k-slot permutation (R10-proven, applied to A- and B-frags identically):
//   f16 pair p = 4q + r  (q = lane>>4, r = reg 0..3) holds (k=p, k=p+16).
//
// Per chunk of 16 timesteps: XG[t][g] = Wih.relu(A_c+B_t)+bih computed with
// 6 MFMAs (A rows = 16 t's, B = Wih gate-tiles) and stored to LDS
// xg[6][16][17] (padded, ~2-way banks).  Amortized 0.4 MFMA/step.
//
// Inner step (serial recurrence, all in-lane thanks to D-layout col=lane&15):
//   hpair(lane p<16 holds (h_p, h_p+16)) -> 4 ds_bpermute -> A-frag ->
//   6 MFMAs HG[g] = Whh.h + bhh  ->  lane l owns r/z/n for m0=l&15 and m0+16
//   -> sigmoid/tanh/update in-lane -> pkh.  XG for the step comes from LDS,
//   prefetched one step ahead.  All 4 lane-groups redundantly compute the
//   same h (wave64 redundancy is free; keeps bpermute sources valid).
// ---------------------------------------------------------------------------
__global__ __launch_bounds__(64, 1) void gru_kernel(
    const float* __restrict__ A, const float* __restrict__ B,
    const float* __restrict__ wih, const float* __restrict__ whh,
    const float* __restrict__ bih, const float* __restrict__ bhh,
    float* __restrict__ h_out) {
    const int l = threadIdx.x;         // 0..63
    const int q = l >> 4;              // k-slot group
    const int m0 = l & 15;             // gate col / hidden index (and m0+16)
    const int c = blockIdx.x;          // chain

    __shared__ float xg[6][16][17];    // [tile][t_local][col m0] (+pad)

    // ---- loop-invariant weight B-frags (R10-proven layout) ----
    hv8 WI[6], WH[6];
#pragma unroll
    for (int T = 0; T < 6; ++T) {
        int g = 16 * T + m0;
        uv4 wi, wh;
#pragma unroll
        for (int r = 0; r < 4; ++r) {
            int lo = 4 * q + r, hi = lo + 16;
            wi[r] = pkh(wih[g * 32 + lo], wih[g * 32 + hi]);
            wh[r] = pkh(whh[g * 32 + lo], whh[g * 32 + hi]);
        }
        WI[T] = __builtin_bit_cast(hv8, wi);
        WH[T] = __builtin_bit_cast(hv8, wh);
    }
    float bi[6], bh[6];
#pragma unroll
    for (int T = 0; T < 6; ++T) {
        bi[T] = bih[16 * T + m0];
        bh[T] = bhh[16 * T + m0];
    }

    const fv4* A4 = (const fv4*)A;     // [chain*8 + slot]
    const fv4* B4 = (const fv4*)B;     // [t*8 + slot]
    const fv4 alo = A4[c * 8 + q];
    const fv4 ahi = A4[c * 8 + 4 + q];

    // chunk staging row: this lane supplies timestep c0 + m0
    fv4 blo = B4[m0 * 8 + q], bhi = B4[m0 * 8 + 4 + q];   // chunk 0 prefetch

    float h0 = 0.f, h1 = 0.f;          // h_{m0}, h_{m0+16}
    unsigned hpair = 0u;               // pkh(h0,h1); lanes 0..15 are sources

    for (int c0 = 0; c0 < 1024; c0 += 16) {
        // ---- X-chunk: 6 MFMAs over 16 timesteps -> LDS ----
        uv4 xb;
#pragma unroll
        for (int r = 0; r < 4; ++r)
            xb[r] = pkh(fmaxf(alo[r] + blo[r], 0.f), fmaxf(ahi[r] + bhi[r], 0.f));
        hv8 xf = __builtin_bit_cast(hv8, xb);

        // prefetch next chunk's B rows (16 steps of slack)
        int nc = (c0 + 16) & 1023;
        blo = B4[(nc + m0) * 8 + q];
        bhi = B4[(nc + m0) * 8 + 4 + q];

#pragma unroll
        for (int T = 0; T < 6; ++T) {
            fv4 D = __builtin_amdgcn_mfma_f32_16x16x32_f16(xf, WI[T], splat4(bi[T]), 0, 0, 0);
#pragma unroll
            for (int r = 0; r < 4; ++r) xg[T][4 * q + r][m0] = D[r];
        }
        __syncthreads();   // single wave: compiles to waitcnt, orders LDS

        // preload X for step 0 of the chunk
        float xc[6];
#pragma unroll
        for (int T = 0; T < 6; ++T) xc[T] = xg[T][0][m0];

#pragma unroll 4
        for (int it = 0; it < 16; ++it) {
            // h A-frag: 4 bpermutes pulling pairs 4q..4q+3 from lanes 0..15
            uv4 hp;
#pragma unroll
            for (int r = 0; r < 4; ++r)
                hp[r] = (unsigned)__builtin_amdgcn_ds_bpermute((4 * q + r) * 4, (int)hpair);
            hv8 hf = __builtin_bit_cast(hv8, hp);

            // h-side gates: HG[g] = Whh.h + bhh  (6 independent MFMAs)
            fv4 HG0 = __builtin_amdgcn_mfma_f32_16x16x32_f16(hf, WH[0], splat4(bh[0]), 0, 0, 0);
            fv4 HG1 = __builtin_amdgcn_mfma_f32_16x16x32_f16(hf, WH[1], splat4(bh[1]), 0, 0, 0);
            fv4 HG2 = __builtin_amdgcn_mfma_f32_16x16x32_f16(hf, WH[2], splat4(bh[2]), 0, 0, 0);
            fv4 HG3 = __builtin_amdgcn_mfma_f32_16x16x32_f16(hf, WH[3], splat4(bh[3]), 0, 0, 0);
            fv4 HG4 = __builtin_amdgcn_mfma_f32_16x16x32_f16(hf, WH[4], splat4(bh[4]), 0, 0, 0);
            fv4 HG5 = __builtin_amdgcn_mfma_f32_16x16x32_f16(hf, WH[5], splat4(bh[5]), 0, 0, 0);

            // prefetch next step's X while MFMAs run
            float xnx[6];
            if (it < 15) {
#pragma unroll
                for (int T = 0; T < 6; ++T) xnx[T] = xg[T][it + 1][m0];
            }

            // gates + update, fully in-lane (D rows replicated -> reg[0])
            float r0 = 1.f / (1.f + __expf(-(xc[0] + HG0[0])));
            float r1 = 1.f / (1.f + __expf(-(xc[1] + HG1[0])));
            float z0 = 1.f / (1.f + __expf(-(xc[2] + HG2[0])));
            float z1 = 1.f / (1.f + __expf(-(xc[3] + HG3[0])));
            float n0 = 1.f - 2.f / (__expf(2.f * (xc[4] + r0 * HG4[0])) + 1.f);
            float n1 = 1.f - 2.f / (__expf(2.f * (xc[5] + r1 * HG5[0])) + 1.f);
            h0 = (1.f - z0) * n0 + z0 * h0;
            h1 = (1.f - z1) * n1 + z1 * h1;
            hpair = pkh(h0, h1);

#pragma unroll
            for (int T = 0; T < 6; ++T) xc[T] = xnx[T];
        }
        __syncthreads();   // writes of next chunk vs reads of this one
    }

    if (l < 16) {
        h_out[c * 32 + m0]      = h0;
        h_out[c * 32 + m0 + 16] = h1;
    }
}

// ---------------------------------------------------------------------------
// K5: classifier. out[i,o] = sum_k clf_w[o,k]*h2[i,k] + clf_b[o]  (fp32 out)
// ---------------------------------------------------------------------------
__global__ void clf_kernel(const float* __restrict__ h2v, const float* __restrict__ w,
                           const float* __restrict__ bias, float* __restrict__ out) {
    int idx = blockIdx.x * 256 + threadIdx.x;      // 0..3071
    if (idx >= 3072) return;
    int i = idx / 3, o = idx - i * 3;
    float s = bias[o];
#pragma unroll
    for (int k = 0; k < 32; ++k) s += w[o * 32 + k] * h2v[i * 32 + k];
    out[idx] = s;
}

extern "C" void kernel_launch(void* const* d_in, const int* in_sizes, int n_in,
                              void* d_out, int out_size, void* d_ws, size_t ws_size,
                              hipStream_t stream) {
    const float* x       = (const float*)d_in[0];
    const float* p1w     = (const float*)d_in[1];
    const float* p1b     = (const float*)d_in[2];
    const float* g1_wih  = (const float*)d_in[3];
    const float* g1_whh  = (const float*)d_in[4];
    const float* g1_bih  = (const float*)d_in[5];
    const float* g1_bhh  = (const float*)d_in[6];
    const float* p2w     = (const float*)d_in[7];
    const float* p2b     = (const float*)d_in[8];
    const float* g2_wih  = (const float*)d_in[9];
    const float* g2_whh  = (const float*)d_in[10];
    const float* g2_bih  = (const float*)d_in[11];
    const float* g2_bhh  = (const float*)d_in[12];
    const float* clfw    = (const float*)d_in[13];
    const float* clfb    = (const float*)d_in[14];

    // Workspace layout (reused across stages; 3 x 32768 floats = 384 KB):
    float* ws = (float*)d_ws;
    float* A  = ws;              // A1 then A2
    float* Bt = ws + 32768;      // B1 then B2
    float* h  = ws + 65536;      // h1 then h2

    proj1_kernel<<<128, 256, 0, stream>>>(x, p1w, p1b, A, Bt);
    gru_kernel<<<1024, 64, 0, stream>>>(A, Bt, g1_wih, g1_whh, g1_bih, g1_bhh, h);
    proj2_kernel<<<128, 256, 0, stream>>>(h, p2w, p2b, A, Bt);
    gru_kernel<<<1024, 64, 0, stream>>>(A, Bt, g2_wih, g2_whh, g2_bih, g2_bhh, h);
    clf_kernel<<<12, 256, 0, stream>>>(h, clfw, clfb, (float*)d_out);
}

// Round 13
// 677.600 us; speedup vs baseline: 1.9950x; 1.1151x over previous
//
#include <hip/hip_runtime.h>

// N=1024, D=16, H=32, 3H=96.  All tensors fp32 (per reference dtypes).

typedef _Float16 hv2 __attribute__((ext_vector_type(2)));
typedef _Float16 hv8 __attribute__((ext_vector_type(8)));
typedef float    fv4 __attribute__((ext_vector_type(4)));
typedef unsigned uv4 __attribute__((ext_vector_type(4)));

// pack two fp32 -> f16 pair bits (v_cvt_pkrtz_f16_f32)
__device__ __forceinline__ unsigned pkh(float a, float b) {
    auto t = __builtin_amdgcn_cvt_pkrtz(a, b);
    return __builtin_bit_cast(unsigned, t);
}
__device__ __forceinline__ fv4 splat4(float v) { return fv4{v, v, v, v}; }
// compiler-only memory fence: stops the scheduler from hoisting the LDS
// h-reads above the same wave's LDS h-write (hardware DS is in-order per
// wave, so no runtime instruction is needed -- R12's failure was exactly
// this reordering).
__device__ __forceinline__ void cfence() { __asm__ __volatile__("" ::: "memory"); }
// dot2: c += a.x*b.x + a.y*b.y   (f16 inputs, f32 accumulate)
#if __has_builtin(__builtin_amdgcn_fdot2)
__device__ __forceinline__ float d2(unsigned a, unsigned b, float c) {
    return __builtin_amdgcn_fdot2(__builtin_bit_cast(hv2, a),
                                  __builtin_bit_cast(hv2, b), c, false);
}
#else
__device__ __forceinline__ float d2(unsigned a, unsigned b, float c) {
    hv2 x = __builtin_bit_cast(hv2, a), y = __builtin_bit_cast(hv2, b);
    return fmaf((float)x.x, (float)y.x, fmaf((float)x.y, (float)y.y, c));
}
#endif
// neighbor (lane^1) via DPP quad_perm(1,0,3,2) -- VALU, no LDS
#if __has_builtin(__builtin_amdgcn_mov_dpp)
__device__ __forceinline__ float nbr1(float v) {
    return __int_as_float(
        __builtin_amdgcn_mov_dpp(__float_as_int(v), 0xB1, 0xF, 0xF, true));
}
#else
__device__ __forceinline__ float nbr1(float v) {
    return __int_as_float(__builtin_amdgcn_ds_swizzle(__float_as_int(v), 0x041F));
}
#endif

// ---------------------------------------------------------------------------
// K1/K3: pairwise rank-split (unchanged, proven).
// ---------------------------------------------------------------------------
__global__ void proj1_kernel(const float* __restrict__ x, const float* __restrict__ w,
                             const float* __restrict__ bias,
                             float* __restrict__ A, float* __restrict__ B) {
    int idx = blockIdx.x * 256 + threadIdx.x;      // 0..32767
    int i = idx >> 5, h = idx & 31;
    float sa = bias[h];
    float sb = 0.f;
#pragma unroll
    for (int d = 0; d < 16; ++d) {
        float xv = x[i * 16 + d];
        float wa = w[h * 32 + d];
        float wb = w[h * 32 + 16 + d];
        sa += (wa - wb) * xv;
        sb += wb * xv;
    }
    A[i * 32 + h] = sa;
    B[i * 32 + h] = sb;
}

__global__ void proj2_kernel(const float* __restrict__ h1, const float* __restrict__ w,
                             const float* __restrict__ bias,
                             float* __restrict__ A, float* __restrict__ B) {
    int idx = blockIdx.x * 256 + threadIdx.x;      // 0..32767
    int i = idx >> 5, h = idx & 31;
    float sa = bias[h];
    float sb = 0.f;
#pragma unroll
    for (int k = 0; k < 32; ++k) {
        float hv = h1[i * 32 + k];
        float wa = w[h * 64 + k];
        float wb = w[h * 64 + 32 + k];
        sa += (wa - wb) * hv;
        sb += wb * hv;
    }
    A[i * 32 + h] = sa;
    B[i * 32 + h] = sb;
}

// ---------------------------------------------------------------------------
// GRU, one chain per wave (1024 blocks).
//   CHUNK phase (per 16 steps, off the serial path): XG[t][g] =
//   Wih.relu(A_c+B_t)+bih via 6 MFMAs (R11-proven frag layout) -> LDS
//   xg[6][16][17].
//   SERIAL phase (per step) -- NO MFMA, NO readlane, NO bpermute:
//     h broadcast: even lanes<32 write pkh(h_l, h_{l+1}) -> hlds[16 dwords];
//     all lanes re-read as 4 wave-uniform ds_read_b128.  Per-wave DS is
//     in-order in hardware; cfence() stops the COMPILER from reordering
//     (the R12 bug).  Lane (m = l&31, halves mirrored) owns gate rows
//     r_m / z_m / n_m: 48 v_dot2, gates + update fully in-lane.
//     X pre-acts read from xg (prefetched one step ahead).
// ---------------------------------------------------------------------------
__global__ __launch_bounds__(64, 1) void gru_kernel(
    const float* __restrict__ A, const float* __restrict__ B,
    const float* __restrict__ wih, const float* __restrict__ whh,
    const float* __restrict__ bih, const float* __restrict__ bhh,
    float* __restrict__ h_out) {
    const int l = threadIdx.x;         // 0..63
    const int q = l >> 4;              // k-slot group (chunk MFMA)
    const int m0 = l & 15;             // MFMA col
    const int m = l & 31;              // gate/hidden index (halves mirrored)
    const int c = blockIdx.x;          // chain

    __shared__ float xg[6][16][17];    // [tile][t_local][col] (+pad)
    __shared__ unsigned hlds[16];      // packed h pairs (h_2p, h_2p+1)

    // ---- chunk-phase weights: Wih B-frags (R10/R11-proven k-slot layout) ----
    hv8 WI[6];
#pragma unroll
    for (int T = 0; T < 6; ++T) {
        int g = 16 * T + m0;
        uv4 wi;
#pragma unroll
        for (int r = 0; r < 4; ++r) {
            int lo = 4 * q + r, hi = lo + 16;
            wi[r] = pkh(wih[g * 32 + lo], wih[g * 32 + hi]);
        }
        WI[T] = __builtin_bit_cast(hv8, wi);
    }
    float bi[6];
#pragma unroll
    for (int T = 0; T < 6; ++T) bi[T] = bih[16 * T + m0];

    // ---- serial-phase weights: whh rows m / 32+m / 64+m, adjacent pairs ----
    unsigned wr2[16], wz2[16], wn2[16];
#pragma unroll
    for (int k = 0; k < 16; ++k) {
        wr2[k] = pkh(whh[m * 32 + 2 * k],        whh[m * 32 + 2 * k + 1]);
        wz2[k] = pkh(whh[(32 + m) * 32 + 2 * k], whh[(32 + m) * 32 + 2 * k + 1]);
        wn2[k] = pkh(whh[(64 + m) * 32 + 2 * k], whh[(64 + m) * 32 + 2 * k + 1]);
    }
    const float bhr = bhh[m];
    const float bhz = bhh[32 + m];
    const float bhn = bhh[64 + m];

    const fv4* A4 = (const fv4*)A;     // [chain*8 + slot]
    const fv4* B4 = (const fv4*)B;     // [t*8 + slot]
    const fv4 alo = A4[c * 8 + q];
    const fv4 ahi = A4[c * 8 + 4 + q];

    // chunk staging: this lane supplies timestep c0 + m0
    fv4 blo = B4[m0 * 8 + q], bhi = B4[m0 * 8 + 4 + q];   // chunk 0

    float h_l = 0.f;                   // h_m (mirrored in both halves)
    if (l < 16) hlds[l] = 0u;

    const uv4* hq = (const uv4*)hlds;  // 4 x b128 wave-uniform reads

    for (int c0 = 0; c0 < 1024; c0 += 16) {
        // ---- X-chunk: 6 MFMAs over 16 timesteps -> LDS ----
        uv4 xb;
#pragma unroll
        for (int r = 0; r < 4; ++r)
            xb[r] = pkh(fmaxf(alo[r] + blo[r], 0.f), fmaxf(ahi[r] + bhi[r], 0.f));
        hv8 xf = __builtin_bit_cast(hv8, xb);

        int nc = (c0 + 16) & 1023;     // prefetch next chunk's B rows
        blo = B4[(nc + m0) * 8 + q];
        bhi = B4[(nc + m0) * 8 + 4 + q];

#pragma unroll
        for (int T = 0; T < 6; ++T) {
            fv4 D = __builtin_amdgcn_mfma_f32_16x16x32_f16(xf, WI[T], splat4(bi[T]), 0, 0, 0);
#pragma unroll
            for (int r = 0; r < 4; ++r) xg[T][4 * q + r][m0] = D[r];
        }
        __syncthreads();

        // preload X pre-acts for step 0 (bih folded in by the MFMA C-seed)
        const int Tq = m >> 4;         // 0 for m<16, 1 for m>=16
        float xr = xg[Tq][0][m & 15];
        float xz = xg[2 + Tq][0][m & 15];
        float xn = xg[4 + Tq][0][m & 15];

#pragma unroll 4
        for (int it = 0; it < 16; ++it) {
            // ---- h quads: ordered after the previous step's ds_write by
            //      per-wave in-order DS + compiler fence ----
            cfence();
            uv4 H0 = hq[0], H1 = hq[1], H2 = hq[2], H3 = hq[3];

            // ---- 48 dot2: r/z/n h-side, 2 split accumulators each ----
            float hr0 = bhr, hr1 = 0.f, hz0 = bhz, hz1 = 0.f, hn0 = bhn, hn1 = 0.f;
#pragma unroll
            for (int k = 0; k < 4; ++k) {
                hr0 = d2(wr2[k],      H0[k], hr0);
                hr1 = d2(wr2[k + 8],  H2[k], hr1);
                hz0 = d2(wz2[k],      H0[k], hz0);
                hz1 = d2(wz2[k + 8],  H2[k], hz1);
                hn0 = d2(wn2[k],      H0[k], hn0);
                hn1 = d2(wn2[k + 8],  H2[k], hn1);
                hr0 = d2(wr2[k + 4],  H1[k], hr0);
                hr1 = d2(wr2[k + 12], H3[k], hr1);
                hz0 = d2(wz2[k + 4],  H1[k], hz0);
                hz1 = d2(wz2[k + 12], H3[k], hz1);
                hn0 = d2(wn2[k + 4],  H1[k], hn0);
                hn1 = d2(wn2[k + 12], H3[k], hn1);
            }
            float hr = hr0 + hr1, hz = hz0 + hz1, hn = hn0 + hn1;

            // ---- prefetch next step's X (off the critical path) ----
            float nxr = xr, nxz = xz, nxn = xn;
            if (it < 15) {
                nxr = xg[Tq][it + 1][m & 15];
                nxz = xg[2 + Tq][it + 1][m & 15];
                nxn = xg[4 + Tq][it + 1][m & 15];
            }

            // ---- gates + update, fully in-lane ----
            float r = 1.f / (1.f + __expf(-(xr + hr)));
            float z = 1.f / (1.f + __expf(-(xz + hz)));
            float n = 1.f - 2.f / (__expf(2.f * (xn + r * hn)) + 1.f);
            h_l = (1.f - z) * n + z * h_l;

            // ---- publish packed h pairs for the next step ----
            unsigned hpk = pkh(h_l, nbr1(h_l));
            if (l < 32 && (l & 1) == 0) hlds[l >> 1] = hpk;
            cfence();

            xr = nxr; xz = nxz; xn = nxn;
        }
        __syncthreads();
    }

    if (l < 32) h_out[c * 32 + m] = h_l;
}

// ---------------------------------------------------------------------------
// K5: classifier. out[i,o] = sum_k clf_w[o,k]*h2[i,k] + clf_b[o]  (fp32 out)
// ---------------------------------------------------------------------------
__global__ void clf_kernel(const float* __restrict__ h2v, const float* __restrict__ w,
                           const float* __restrict__ bias, float* __restrict__ out) {
    int idx = blockIdx.x * 256 + threadIdx.x;      // 0..3071
    if (idx >= 3072) return;
    int i = idx / 3, o = idx - i * 3;
    float s = bias[o];
#pragma unroll
    for (int k = 0; k < 32; ++k) s += w[o * 32 + k] * h2v[i * 32 + k];
    out[idx] = s;
}

extern "C" void kernel_launch(void* const* d_in, const int* in_sizes, int n_in,
                              void* d_out, int out_size, void* d_ws, size_t ws_size,
                              hipStream_t stream) {
    const float* x       = (const float*)d_in[0];
    const float* p1w     = (const float*)d_in[1];
    const float* p1b     = (const float*)d_in[2];
    const float* g1_wih  = (const float*)d_in[3];
    const float* g1_whh  = (const float*)d_in[4];
    const float* g1_bih  = (const float*)d_in[5];
    const float* g1_bhh  = (const float*)d_in[6];
    const float* p2w     = (const float*)d_in[7];
    const float* p2b     = (const float*)d_in[8];
    const float* g2_wih  = (const float*)d_in[9];
    const float* g2_whh  = (const float*)d_in[10];
    const float* g2_bih  = (const float*)d_in[11];
    const float* g2_bhh  = (const float*)d_in[12];
    const float* clfw    = (const float*)d_in[13];
    const float* clfb    = (const float*)d_in[14];

    // Workspace layout (reused across stages; 3 x 32768 floats = 384 KB):
    float* ws = (float*)d_ws;
    float* A  = ws;              // A1 then A2
    float* Bt = ws + 32768;      // B1 then B2
    float* h  = ws + 65536;      // h1 then h2

    proj1_kernel<<<128, 256, 0, stream>>>(x, p1w, p1b, A, Bt);
    gru_kernel<<<1024, 64, 0, stream>>>(A, Bt, g1_wih, g1_whh, g1_bih, g1_bhh, h);
    proj2_kernel<<<128, 256, 0, stream>>>(h, p2w, p2b, A, Bt);
    gru_kernel<<<1024, 64, 0, stream>>>(A, Bt, g2_wih, g2_whh, g2_bih, g2_bhh, h);
    clf_kernel<<<12, 256, 0, stream>>>(h, clfw, clfb, (float*)d_out);
}